// Round 19
// baseline (151.584 us; speedup 1.0000x reference)
//
#include <hip/hip_runtime.h>
#include <hip/hip_bf16.h>
#include <hip/hip_fp16.h>

#define NTOT 65536   // T*H*W

typedef __hip_bfloat16 bf16;
typedef _Float16 f16;
typedef f16 f16x4 __attribute__((ext_vector_type(4)));
typedef f16 f16x8 __attribute__((ext_vector_type(8)));
typedef float f32x4 __attribute__((ext_vector_type(4)));
typedef _Float16 h2f16 __attribute__((ext_vector_type(2)));

__device__ __forceinline__ ushort f2hs(float f) {
  __half h = __float2half(f);
  return __half_as_ushort(h);
}
__device__ __forceinline__ float fdot2(unsigned a, unsigned b, float c) {
  return __builtin_amdgcn_fdot2(__builtin_bit_cast(h2f16, a),
                                __builtin_bit_cast(h2f16, b), c, false);
}
__device__ __forceinline__ f16x8 cmb(f16x4 a, f16x4 b) {
  f16x8 r;
#pragma unroll
  for (int j = 0; j < 4; ++j) { r[j] = a[j]; r[j + 4] = b[j]; }
  return r;
}

// ---------------- K1: 1x1x1 conv as MFMA GEMM; qkvT[cluster][n][16ch] f16
__global__ __launch_bounds__(256) void k_qkv(const float* __restrict__ x,
                                             const float* __restrict__ w,
                                             ushort* __restrict__ qkvT) {
  const int n0  = blockIdx.x * 64;
  const int oct = blockIdx.y;           // 0..11
  __shared__ __align__(16) ushort wt[64 * 72];     // 9216 B
  const int tid = threadIdx.x;
  const float4* w4 = (const float4*)w;
#pragma unroll
  for (int i = 0; i < 4; ++i) {
    const int idx = tid + i * 256;      // 0..1023
    const int oc = idx >> 4, kq = idx & 15;
    float4 wv = w4[(oct * 64 + oc) * 16 + kq];
    ushort4 o;
    o.x = f2hs(wv.x); o.y = f2hs(wv.y); o.z = f2hs(wv.z); o.w = f2hs(wv.w);
    *(ushort4*)(wt + oc * 72 + kq * 4) = o;
  }
  __syncthreads();

  const int lane = tid & 63;
  const int wq   = tid >> 6;
  const int ln15 = lane & 15;
  const int lq   = lane >> 4;
  const int n    = n0 + wq * 16 + ln15;

  f32x4 acc[4];
#pragma unroll
  for (int i = 0; i < 4; ++i) acc[i] = (f32x4){0.f, 0.f, 0.f, 0.f};

#pragma unroll
  for (int kk = 0; kk < 4; ++kk) {
    const int kb = kk * 4 + lq;         // k-quad index; k = kb*4 + j
    f16x4 b;
#pragma unroll
    for (int j = 0; j < 4; ++j)
      b[j] = (f16)x[(size_t)(kb * 4 + j) * NTOT + n];
#pragma unroll
    for (int mt = 0; mt < 4; ++mt) {
      f16x4 a = *(const f16x4*)(wt + (mt * 16 + ln15) * 72 + kk * 16 + lq * 4);
      acc[mt] = __builtin_amdgcn_mfma_f32_16x16x16f16(a, b, acc[mt], 0, 0, 0);
    }
  }
#pragma unroll
  for (int mt = 0; mt < 4; ++mt) {
    const int cl = oct * 4 + mt;
    ushort4 o;
    o.x = f2hs(acc[mt][0]);
    o.y = f2hs(acc[mt][1]);
    o.z = f2hs(acc[mt][2]);
    o.w = f2hs(acc[mt][3]);
    *(ushort4*)(qkvT + ((size_t)cl * NTOT + n) * 16 + lq * 4) = o;
  }
}

// ---------------- K2: grouped 3x3x3 conv, block-diag implicit GEMM on MFMA K=16.
// Flat 6144-block grid, XCD-chunked swizzle: xcd = bx&7 owns a 16-tile spatial
// span; within an XCD, spatial tiles vary fastest (halo rows L2-shared).
__global__ __launch_bounds__(256, 4) void k_dwconv(const ushort* __restrict__ qkvT,
                                                   const float* __restrict__ dww,
                                                   ushort* __restrict__ out) {
  const int bx   = blockIdx.x;          // 0..6143
  const int xcd  = bx & 7;
  const int j    = bx >> 3;             // 0..767
  const int s    = xcd * 16 + (j & 15); // spatial tile 0..127
  const int cl   = j >> 4;              // 0..47
  const int wsel = s & 3, hsel = (s >> 2) & 7, tsel = s >> 5;
  const int t0 = tsel * 4, h0 = hsel * 8, w0 = wsel * 16;
  __shared__ __align__(16) ushort xh[6 * 10 * 18 * 16];  // 34560 B
  __shared__ __align__(16) ushort at[27 * 64];           //  3456 B [tap][p16][ic4]
  const int tid = threadIdx.x;

  for (int idx = tid; idx < 27 * 64; idx += 256) {
    int tap = idx >> 6;
    int p   = (idx >> 2) & 15;
    int ic  = idx & 3;
    at[idx] = f2hs(dww[(cl * 4 + (p >> 2)) * 432 + ((p & 3) * 4 + ic) * 27 + tap]);
  }
  const ushort* cb = qkvT + (size_t)cl * (NTOT * 16);
  for (int ci = tid; ci < 1080; ci += 256) {
    int W = ci % 18;
    int r = ci / 18;
    int H = r % 10;
    int T = r / 10;
    int Tg = t0 - 1 + T, Hg = h0 - 1 + H, Wg = w0 - 1 + W;
    uint4 d0 = {0, 0, 0, 0}, d1 = {0, 0, 0, 0};
    if ((unsigned)Tg < 16u && (unsigned)Hg < 64u && (unsigned)Wg < 64u) {
      const uint4* src = (const uint4*)(cb + (size_t)(Tg * 4096 + Hg * 64 + Wg) * 16);
      d0 = src[0];
      d1 = src[1];
    }
    const int rot = (W >> 2) & 3;
    uint2* dst = (uint2*)(xh + ci * 16);
    uint2 u0 = {d0.x, d0.y}, u1 = {d0.z, d0.w}, u2 = {d1.x, d1.y}, u3 = {d1.z, d1.w};
    dst[(0 + rot) & 3] = u0;
    dst[(1 + rot) & 3] = u1;
    dst[(2 + rot) & 3] = u2;
    dst[(3 + rot) & 3] = u3;
  }
  __syncthreads();

  const int lane = tid & 63;
  const int wv   = tid >> 6;        // h-pair index: wave covers h = wv*2, wv*2+1
  const int hp   = wv * 2;
  const int ln15 = lane & 15;
  const int lq   = lane >> 4;
  const bool diag = (lq == (ln15 >> 2));
  const ushort* bp[3];
#pragma unroll
  for (int dwp = 0; dwp < 3; ++dwp) {
    const int Wl = ln15 + dwp;
    const int slot = (lq + (Wl >> 2)) & 3;
    bp[dwp] = xh + Wl * 16 + slot * 4;
  }
  const f16x4 z4 = {};

  f32x4 acc[4][2];   // [t][h2]
#pragma unroll
  for (int a = 0; a < 4; ++a)
#pragma unroll
    for (int b = 0; b < 2; ++b) acc[a][b] = (f32x4){0.f, 0.f, 0.f, 0.f};

#pragma unroll
  for (int dh = 0; dh < 3; ++dh) {
#pragma unroll
    for (int dwp = 0; dwp < 3; ++dwp) {
      // cache 6 t-planes x 2 h rows
      f16x4 B[6][2];
#pragma unroll
      for (int tt = 0; tt < 6; ++tt)
#pragma unroll
        for (int h2 = 0; h2 < 2; ++h2)
          B[tt][h2] = *(const f16x4*)(bp[dwp] + (tt * 10 + hp + h2 + dh) * 288);
#pragma unroll
      for (int dt = 0; dt < 3; ++dt) {
        const int tap = (dt * 3 + dh) * 3 + dwp;
        f16x4 a = *(const f16x4*)(at + tap * 64 + ln15 * 4);
        if (!diag) a = z4;
#pragma unroll
        for (int t = 0; t < 4; ++t)
#pragma unroll
          for (int h2 = 0; h2 < 2; ++h2)
            acc[t][h2] = __builtin_amdgcn_mfma_f32_16x16x16f16(a, B[t + dt][h2],
                                                               acc[t][h2], 0, 0, 0);
      }
    }
  }
  const int chbase = cl * 16 + lq * 4;
#pragma unroll
  for (int t = 0; t < 4; ++t)
#pragma unroll
    for (int h2 = 0; h2 < 2; ++h2) {
      const int n = (t0 + t) * 4096 + (h0 + hp + h2) * 64 + w0 + ln15;
#pragma unroll
      for (int r = 0; r < 4; ++r)
        out[(size_t)(chbase + r) * NTOT + n] = f2hs(acc[t][h2][r]);
    }
}

// ---------------- K3: gram via MFMA. S[c][d] = sum_n q[c][n]k[d][n]; + sum q^2,k^2
__global__ __launch_bounds__(256) void k_attn_part(const ushort* __restrict__ dwout,
                                                   float* __restrict__ pS,
                                                   float* __restrict__ pQ,
                                                   float* __restrict__ pK) {
  const int head = blockIdx.y;
  const int chunk = blockIdx.x;   // 0..127, each 512 n
  const int tid = threadIdx.x;
  const ushort* qb = dwout + (size_t)(head * 64) * NTOT;
  const ushort* kb = dwout + (size_t)(256 + head * 64) * NTOT;
  __shared__ __align__(16) ushort lsq[64][76];   // 9728 B, row 152B
  __shared__ __align__(16) ushort lsk[64][76];
  const int lane = tid & 63, wv = tid >> 6;
  const int ln15 = lane & 15, lqd = lane >> 4;
  const int c0 = wv * 16;
  const int sch = tid >> 2, spart = tid & 3;
  f32x4 acc[4];
#pragma unroll
  for (int i = 0; i < 4; ++i) acc[i] = (f32x4){0.f, 0.f, 0.f, 0.f};
  float qq = 0.f, kk = 0.f;

  for (int ph = 0; ph < 8; ++ph) {
    const int nb = chunk * 512 + ph * 64;
    __syncthreads();
#pragma unroll
    for (int i = 0; i < 2; ++i) {
      const int id = tid + i * 256;   // 0..511
      const int ch = id >> 3, n8 = id & 7;
      uint4 qv = *(const uint4*)(qb + (size_t)ch * NTOT + nb + n8 * 8);
      uint4 kv = *(const uint4*)(kb + (size_t)ch * NTOT + nb + n8 * 8);
      *(uint2*)&lsq[ch][n8 * 8]     = (uint2){qv.x, qv.y};
      *(uint2*)&lsq[ch][n8 * 8 + 4] = (uint2){qv.z, qv.w};
      *(uint2*)&lsk[ch][n8 * 8]     = (uint2){kv.x, kv.y};
      *(uint2*)&lsk[ch][n8 * 8 + 4] = (uint2){kv.z, kv.w};
    }
    __syncthreads();
#pragma unroll
    for (int ks = 0; ks < 2; ++ks) {
      f16x4 a0 = *(const f16x4*)&lsq[c0 + ln15][ks * 32 + lqd * 4];
      f16x4 a1 = *(const f16x4*)&lsq[c0 + ln15][ks * 32 + lqd * 4 + 16];
      f16x8 a = cmb(a0, a1);
#pragma unroll
      for (int d = 0; d < 4; ++d) {
        f16x4 b0 = *(const f16x4*)&lsk[d * 16 + ln15][ks * 32 + lqd * 4];
        f16x4 b1 = *(const f16x4*)&lsk[d * 16 + ln15][ks * 32 + lqd * 4 + 16];
        f16x8 b = cmb(b0, b1);
        acc[d] = __builtin_amdgcn_mfma_f32_16x16x32_f16(a, b, acc[d], 0, 0, 0);
      }
    }
#pragma unroll
    for (int j4 = 0; j4 < 4; ++j4) {
      uint2 qv = *(const uint2*)&lsq[sch][spart * 16 + j4 * 4];
      uint2 kv = *(const uint2*)&lsk[sch][spart * 16 + j4 * 4];
      qq = fdot2(qv.x, qv.x, qq); qq = fdot2(qv.y, qv.y, qq);
      kk = fdot2(kv.x, kv.x, kk); kk = fdot2(kv.y, kv.y, kk);
    }
  }
  qq += __shfl_xor(qq, 1); qq += __shfl_xor(qq, 2);
  kk += __shfl_xor(kk, 1); kk += __shfl_xor(kk, 2);
  if (spart == 0) {
    pQ[(head * 128 + chunk) * 64 + sch] = qq;
    pK[(head * 128 + chunk) * 64 + sch] = kk;
  }
  float* ps = pS + (size_t)(head * 128 + chunk) * 4096;
#pragma unroll
  for (int d = 0; d < 4; ++d)
#pragma unroll
    for (int r = 0; r < 4; ++r)
      ps[(c0 + lqd * 4 + r) * 64 + d * 16 + ln15] = acc[d][r];
}

// ---------------- K4a: parallel reduce+softmax. Grid (64 c, 4 heads), 256 thr.
__global__ __launch_bounds__(256) void k_softmax(const float* __restrict__ pS,
                                                 const float* __restrict__ pQ,
                                                 const float* __restrict__ pK,
                                                 const float* __restrict__ temp,
                                                 float* __restrict__ A) {
  const int c    = blockIdx.x;    // 0..63
  const int head = blockIdx.y;    // 0..3
  const int tid  = threadIdx.x;
  const int d    = tid & 63, part = tid >> 6;
  __shared__ float red[4][64];
  __shared__ float rq2[128];
  __shared__ float rk[64];
  __shared__ float rqs;

  {
    float s = 0.f;
    for (int ch = part * 32; ch < part * 32 + 32; ++ch)
      s += pK[(head * 128 + ch) * 64 + d];
    red[part][d] = s;
  }
  if (tid < 128) rq2[tid] = pQ[(head * 128 + tid) * 64 + c];
  __syncthreads();
  if (tid < 64) {
    float s = red[0][tid] + red[1][tid] + red[2][tid] + red[3][tid];
    rk[tid] = 1.f / fmaxf(sqrtf(s), 1e-12f);
  }
  if (tid >= 64 && tid < 128) {
    float s = rq2[tid - 64] + rq2[tid];
#pragma unroll
    for (int o = 1; o <= 32; o <<= 1) s += __shfl_xor(s, o);
    if (tid == 64) rqs = 1.f / fmaxf(sqrtf(s), 1e-12f);
  }
  __syncthreads();

  {
    float s = 0.f;
    for (int ch = part * 32; ch < part * 32 + 32; ++ch)
      s += pS[(size_t)(head * 128 + ch) * 4096 + c * 64 + d];
    red[part][d] = s;
  }
  __syncthreads();
  if (tid < 64) {
    const float Sd = red[0][tid] + red[1][tid] + red[2][tid] + red[3][tid];
    float v = Sd * rqs * rk[tid] * temp[head];
    float m = v;
#pragma unroll
    for (int o = 1; o <= 32; o <<= 1) m = fmaxf(m, __shfl_xor(m, o));
    float e = expf(v - m);
    float s = e;
#pragma unroll
    for (int o = 1; o <= 32; o <<= 1) s += __shfl_xor(s, o);
    A[head * 4096 + c * 64 + tid] = e / s;
  }
}

// ---------------- K4b: MtT[oc][h*64+d] = sum_c pw[oc][h*64+c]*A[h][c][d]  (f16)
__global__ __launch_bounds__(64) void k_mt(const float* __restrict__ pw,
                                           const float* __restrict__ A,
                                           ushort* __restrict__ MtT) {
  const int hd = blockIdx.x;   // 0..255
  const int h = hd >> 6, d = hd & 63;
  const int oc = threadIdx.x;  // 0..63
  float s = 0.f;
  for (int c = 0; c < 64; ++c)
    s = fmaf(pw[oc * 256 + h * 64 + c], A[(h * 64 + c) * 64 + d], s);
  MtT[oc * 256 + hd] = f2hs(s);
}

// ---------------- K5: y[oc][n] = sum_hd MtT[oc][hd] * v[hd][n]  via MFMA
__global__ __launch_bounds__(256) void k_pv(const ushort* __restrict__ dwout,
                                            const ushort* __restrict__ MtT,
                                            float* __restrict__ y) {
  const int n0 = blockIdx.x * 64;
  const ushort* vb = dwout + 512 * (size_t)NTOT;
  __shared__ __align__(16) ushort vt[64 * 256];   // 32 KB: [n][hd] quad-rotated
  const int tid = threadIdx.x;
#pragma unroll
  for (int i = 0; i < 2; ++i) {
    const int id = tid + i * 256;    // 0..511
    const int kq = id >> 3;          // hd-quad 0..63
    const int ng = id & 7;           // n-octet
    uint4 r0 = *(const uint4*)(vb + (size_t)(kq * 4 + 0) * NTOT + n0 + ng * 8);
    uint4 r1 = *(const uint4*)(vb + (size_t)(kq * 4 + 1) * NTOT + n0 + ng * 8);
    uint4 r2 = *(const uint4*)(vb + (size_t)(kq * 4 + 2) * NTOT + n0 + ng * 8);
    uint4 r3 = *(const uint4*)(vb + (size_t)(kq * 4 + 3) * NTOT + n0 + ng * 8);
    const ushort* h0 = (const ushort*)&r0;
    const ushort* h1 = (const ushort*)&r1;
    const ushort* h2 = (const ushort*)&r2;
    const ushort* h3 = (const ushort*)&r3;
#pragma unroll
    for (int j = 0; j < 8; ++j) {
      const int n = ng * 8 + j;
      unsigned lo = (unsigned)h0[j] | ((unsigned)h1[j] << 16);
      unsigned hi = (unsigned)h2[j] | ((unsigned)h3[j] << 16);
      const int slot = (kq + n + (n >> 3)) & 63;
      *(uint2*)(vt + n * 256 + slot * 4) = (uint2){lo, hi};
    }
  }
  __syncthreads();

  const int lane = tid & 63;
  const int wv   = tid >> 6;
  const int ln15 = lane & 15, lq = lane >> 4;
  const int nloc = wv * 16 + ln15;
  const int nrot = nloc + (nloc >> 3);

  f32x4 acc[4];
#pragma unroll
  for (int i = 0; i < 4; ++i) acc[i] = (f32x4){0.f, 0.f, 0.f, 0.f};

#pragma unroll
  for (int kb = 0; kb < 8; ++kb) {
    const int kq0 = kb * 8 + lq;
    const int s0 = ((kq0 + nrot) & 63) * 4;
    const int s1 = ((kq0 + 4 + nrot) & 63) * 4;
    f16x4 b0 = *(const f16x4*)(vt + nloc * 256 + s0);
    f16x4 b1 = *(const f16x4*)(vt + nloc * 256 + s1);
    f16x8 b = cmb(b0, b1);
#pragma unroll
    for (int mt = 0; mt < 4; ++mt) {
      const ushort* ap = MtT + (mt * 16 + ln15) * 256 + kb * 32 + lq * 4;
      f16x4 a0 = *(const f16x4*)(ap);
      f16x4 a1 = *(const f16x4*)(ap + 16);
      f16x8 a = cmb(a0, a1);
      acc[mt] = __builtin_amdgcn_mfma_f32_16x16x32_f16(a, b, acc[mt], 0, 0, 0);
    }
  }
  const int n = n0 + nloc;
#pragma unroll
  for (int mt = 0; mt < 4; ++mt) {
    const int oc = mt * 16 + lq * 4;
#pragma unroll
    for (int r = 0; r < 4; ++r)
      y[(size_t)(oc + r) * NTOT + n] = acc[mt][r];
  }
}

extern "C" void kernel_launch(void* const* d_in, const int* in_sizes, int n_in,
                              void* d_out, int out_size, void* d_ws, size_t ws_size,
                              hipStream_t stream) {
  const float* x      = (const float*)d_in[0];
  const float* qkv_w  = (const float*)d_in[1];
  const float* dw_w   = (const float*)d_in[2];
  const float* proj_w = (const float*)d_in[3];
  const float* temp   = (const float*)d_in[4];
  float* out = (float*)d_out;

  char* w8 = (char*)d_ws;
  ushort* qkvT = (ushort*)(w8);                        // [48][65536][16] f16 = 100,663,296 B
  ushort* dwout = (ushort*)(w8 + 100663296ull);        // [768][n] f16 = 100,663,296 B
  float* pS    = (float*)(w8 + 201326592ull);          // 4*128*4096 f32 = 8,388,608 B
  float* pQ    = (float*)(w8 + 209715200ull);          // 32768 f32
  float* pK    = (float*)(w8 + 209846272ull);          // 32768 f32
  float* A     = (float*)(w8 + 209977344ull);          // 16384 f32
  ushort* MtT  = (ushort*)(w8 + 210042880ull);         // 64*256 f16 = 32768 B
  // total ~210 MB

  k_qkv<<<dim3(1024, 12), 256, 0, stream>>>(x, qkv_w, qkvT);
  k_dwconv<<<dim3(6144), 256, 0, stream>>>(qkvT, dw_w, dwout);
  k_attn_part<<<dim3(128, 4), 256, 0, stream>>>(dwout, pS, pQ, pK);
  k_softmax<<<dim3(64, 4), 256, 0, stream>>>(pS, pQ, pK, temp, A);
  k_mt<<<256, 64, 0, stream>>>(proj_w, A, MtT);
  k_pv<<<1024, 256, 0, stream>>>(dwout, MtT, out);
}

// Round 20
// 149.524 us; speedup vs baseline: 1.0138x; 1.0138x over previous
//
#include <hip/hip_runtime.h>
#include <hip/hip_bf16.h>
#include <hip/hip_fp16.h>

#define NTOT 65536   // T*H*W

typedef __hip_bfloat16 bf16;
typedef _Float16 f16;
typedef f16 f16x4 __attribute__((ext_vector_type(4)));
typedef f16 f16x8 __attribute__((ext_vector_type(8)));
typedef float f32x4 __attribute__((ext_vector_type(4)));
typedef _Float16 h2f16 __attribute__((ext_vector_type(2)));

__device__ __forceinline__ ushort f2hs(float f) {
  __half h = __float2half(f);
  return __half_as_ushort(h);
}
__device__ __forceinline__ float fdot2(unsigned a, unsigned b, float c) {
  return __builtin_amdgcn_fdot2(__builtin_bit_cast(h2f16, a),
                                __builtin_bit_cast(h2f16, b), c, false);
}
__device__ __forceinline__ f16x8 cmb(f16x4 a, f16x4 b) {
  f16x8 r;
#pragma unroll
  for (int j = 0; j < 4; ++j) { r[j] = a[j]; r[j + 4] = b[j]; }
  return r;
}

// ---------------- K1: 1x1x1 conv as MFMA GEMM; qkvT[cluster][n][16ch] f16
__global__ __launch_bounds__(256) void k_qkv(const float* __restrict__ x,
                                             const float* __restrict__ w,
                                             ushort* __restrict__ qkvT) {
  const int n0  = blockIdx.x * 64;
  const int oct = blockIdx.y;           // 0..11
  __shared__ __align__(16) ushort wt[64 * 72];     // 9216 B
  const int tid = threadIdx.x;
  const float4* w4 = (const float4*)w;
#pragma unroll
  for (int i = 0; i < 4; ++i) {
    const int idx = tid + i * 256;      // 0..1023
    const int oc = idx >> 4, kq = idx & 15;
    float4 wv = w4[(oct * 64 + oc) * 16 + kq];
    ushort4 o;
    o.x = f2hs(wv.x); o.y = f2hs(wv.y); o.z = f2hs(wv.z); o.w = f2hs(wv.w);
    *(ushort4*)(wt + oc * 72 + kq * 4) = o;
  }
  __syncthreads();

  const int lane = tid & 63;
  const int wq   = tid >> 6;
  const int ln15 = lane & 15;
  const int lq   = lane >> 4;
  const int n    = n0 + wq * 16 + ln15;

  f32x4 acc[4];
#pragma unroll
  for (int i = 0; i < 4; ++i) acc[i] = (f32x4){0.f, 0.f, 0.f, 0.f};

#pragma unroll
  for (int kk = 0; kk < 4; ++kk) {
    const int kb = kk * 4 + lq;         // k-quad index; k = kb*4 + j
    f16x4 b;
#pragma unroll
    for (int j = 0; j < 4; ++j)
      b[j] = (f16)x[(size_t)(kb * 4 + j) * NTOT + n];
#pragma unroll
    for (int mt = 0; mt < 4; ++mt) {
      f16x4 a = *(const f16x4*)(wt + (mt * 16 + ln15) * 72 + kk * 16 + lq * 4);
      acc[mt] = __builtin_amdgcn_mfma_f32_16x16x16f16(a, b, acc[mt], 0, 0, 0);
    }
  }
#pragma unroll
  for (int mt = 0; mt < 4; ++mt) {
    const int cl = oct * 4 + mt;
    ushort4 o;
    o.x = f2hs(acc[mt][0]);
    o.y = f2hs(acc[mt][1]);
    o.z = f2hs(acc[mt][2]);
    o.w = f2hs(acc[mt][3]);
    *(ushort4*)(qkvT + ((size_t)cl * NTOT + n) * 16 + lq * 4) = o;
  }
}

// ---------------- K2: grouped 3x3x3 conv, block-diag implicit GEMM on MFMA K=16.
// Grid (cl=48, s=128) (r18 order — r19 swizzle reverted, FETCH regressed).
// Halo staging batched: all global loads issued before any LDS write.
__global__ __launch_bounds__(256, 4) void k_dwconv(const ushort* __restrict__ qkvT,
                                                   const float* __restrict__ dww,
                                                   ushort* __restrict__ out) {
  const int cl = blockIdx.x;        // 0..47
  const int s  = blockIdx.y;        // 0..127
  const int wsel = s & 3, hsel = (s >> 2) & 7, tsel = s >> 5;
  const int t0 = tsel * 4, h0 = hsel * 8, w0 = wsel * 16;
  __shared__ __align__(16) ushort xh[6 * 10 * 18 * 16];  // 34560 B
  __shared__ __align__(16) ushort at[27 * 64];           //  3456 B [tap][p16][ic4]
  const int tid = threadIdx.x;

  // ---- batched halo staging: issue all global loads, then all LDS writes
  const ushort* cb = qkvT + (size_t)cl * (NTOT * 16);
  uint4 ha[5], hb[5];
#pragma unroll
  for (int i = 0; i < 5; ++i) {
    const int ci = tid + i * 256;
    uint4 d0 = {0, 0, 0, 0}, d1 = {0, 0, 0, 0};
    if (ci < 1080) {
      const int W = ci % 18;
      const int r = ci / 18;
      const int H = r % 10;
      const int T = r / 10;
      const int Tg = t0 - 1 + T, Hg = h0 - 1 + H, Wg = w0 - 1 + W;
      if ((unsigned)Tg < 16u && (unsigned)Hg < 64u && (unsigned)Wg < 64u) {
        const uint4* src = (const uint4*)(cb + (size_t)(Tg * 4096 + Hg * 64 + Wg) * 16);
        d0 = src[0];
        d1 = src[1];
      }
    }
    ha[i] = d0;
    hb[i] = d1;
  }
  // A-table pack (independent of halo loads; overlaps their latency)
  for (int idx = tid; idx < 27 * 64; idx += 256) {
    int tap = idx >> 6;
    int p   = (idx >> 2) & 15;
    int ic  = idx & 3;
    at[idx] = f2hs(dww[(cl * 4 + (p >> 2)) * 432 + ((p & 3) * 4 + ic) * 27 + tap]);
  }
#pragma unroll
  for (int i = 0; i < 5; ++i) {
    const int ci = tid + i * 256;
    if (ci < 1080) {
      const int W = ci % 18;
      const int rot = (W >> 2) & 3;
      uint2* dst = (uint2*)(xh + ci * 16);
      uint2 u0 = {ha[i].x, ha[i].y}, u1 = {ha[i].z, ha[i].w};
      uint2 u2 = {hb[i].x, hb[i].y}, u3 = {hb[i].z, hb[i].w};
      dst[(0 + rot) & 3] = u0;
      dst[(1 + rot) & 3] = u1;
      dst[(2 + rot) & 3] = u2;
      dst[(3 + rot) & 3] = u3;
    }
  }
  __syncthreads();

  const int lane = tid & 63;
  const int wv   = tid >> 6;        // h-pair index: wave covers h = wv*2, wv*2+1
  const int hp   = wv * 2;
  const int ln15 = lane & 15;
  const int lq   = lane >> 4;
  const bool diag = (lq == (ln15 >> 2));
  const ushort* bp[3];
#pragma unroll
  for (int dwp = 0; dwp < 3; ++dwp) {
    const int Wl = ln15 + dwp;
    const int slot = (lq + (Wl >> 2)) & 3;
    bp[dwp] = xh + Wl * 16 + slot * 4;
  }
  const f16x4 z4 = {};

  f32x4 acc[4][2];   // [t][h2]
#pragma unroll
  for (int a = 0; a < 4; ++a)
#pragma unroll
    for (int b = 0; b < 2; ++b) acc[a][b] = (f32x4){0.f, 0.f, 0.f, 0.f};

#pragma unroll
  for (int dh = 0; dh < 3; ++dh) {
#pragma unroll
    for (int dwp = 0; dwp < 3; ++dwp) {
      // cache 6 t-planes x 2 h rows
      f16x4 B[6][2];
#pragma unroll
      for (int tt = 0; tt < 6; ++tt)
#pragma unroll
        for (int h2 = 0; h2 < 2; ++h2)
          B[tt][h2] = *(const f16x4*)(bp[dwp] + (tt * 10 + hp + h2 + dh) * 288);
#pragma unroll
      for (int dt = 0; dt < 3; ++dt) {
        const int tap = (dt * 3 + dh) * 3 + dwp;
        f16x4 a = *(const f16x4*)(at + tap * 64 + ln15 * 4);
        if (!diag) a = z4;
#pragma unroll
        for (int t = 0; t < 4; ++t)
#pragma unroll
          for (int h2 = 0; h2 < 2; ++h2)
            acc[t][h2] = __builtin_amdgcn_mfma_f32_16x16x16f16(a, B[t + dt][h2],
                                                               acc[t][h2], 0, 0, 0);
      }
    }
  }
  const int chbase = cl * 16 + lq * 4;
#pragma unroll
  for (int t = 0; t < 4; ++t)
#pragma unroll
    for (int h2 = 0; h2 < 2; ++h2) {
      const int n = (t0 + t) * 4096 + (h0 + hp + h2) * 64 + w0 + ln15;
#pragma unroll
      for (int r = 0; r < 4; ++r)
        out[(size_t)(chbase + r) * NTOT + n] = f2hs(acc[t][h2][r]);
    }
}

// ---------------- K3: gram via MFMA. S[c][d] = sum_n q[c][n]k[d][n]; + sum q^2,k^2
__global__ __launch_bounds__(256) void k_attn_part(const ushort* __restrict__ dwout,
                                                   float* __restrict__ pS,
                                                   float* __restrict__ pQ,
                                                   float* __restrict__ pK) {
  const int head = blockIdx.y;
  const int chunk = blockIdx.x;   // 0..127, each 512 n
  const int tid = threadIdx.x;
  const ushort* qb = dwout + (size_t)(head * 64) * NTOT;
  const ushort* kb = dwout + (size_t)(256 + head * 64) * NTOT;
  __shared__ __align__(16) ushort lsq[64][76];   // 9728 B, row 152B
  __shared__ __align__(16) ushort lsk[64][76];
  const int lane = tid & 63, wv = tid >> 6;
  const int ln15 = lane & 15, lqd = lane >> 4;
  const int c0 = wv * 16;
  const int sch = tid >> 2, spart = tid & 3;
  f32x4 acc[4];
#pragma unroll
  for (int i = 0; i < 4; ++i) acc[i] = (f32x4){0.f, 0.f, 0.f, 0.f};
  float qq = 0.f, kk = 0.f;

  for (int ph = 0; ph < 8; ++ph) {
    const int nb = chunk * 512 + ph * 64;
    __syncthreads();
#pragma unroll
    for (int i = 0; i < 2; ++i) {
      const int id = tid + i * 256;   // 0..511
      const int ch = id >> 3, n8 = id & 7;
      uint4 qv = *(const uint4*)(qb + (size_t)ch * NTOT + nb + n8 * 8);
      uint4 kv = *(const uint4*)(kb + (size_t)ch * NTOT + nb + n8 * 8);
      *(uint2*)&lsq[ch][n8 * 8]     = (uint2){qv.x, qv.y};
      *(uint2*)&lsq[ch][n8 * 8 + 4] = (uint2){qv.z, qv.w};
      *(uint2*)&lsk[ch][n8 * 8]     = (uint2){kv.x, kv.y};
      *(uint2*)&lsk[ch][n8 * 8 + 4] = (uint2){kv.z, kv.w};
    }
    __syncthreads();
#pragma unroll
    for (int ks = 0; ks < 2; ++ks) {
      f16x4 a0 = *(const f16x4*)&lsq[c0 + ln15][ks * 32 + lqd * 4];
      f16x4 a1 = *(const f16x4*)&lsq[c0 + ln15][ks * 32 + lqd * 4 + 16];
      f16x8 a = cmb(a0, a1);
#pragma unroll
      for (int d = 0; d < 4; ++d) {
        f16x4 b0 = *(const f16x4*)&lsk[d * 16 + ln15][ks * 32 + lqd * 4];
        f16x4 b1 = *(const f16x4*)&lsk[d * 16 + ln15][ks * 32 + lqd * 4 + 16];
        f16x8 b = cmb(b0, b1);
        acc[d] = __builtin_amdgcn_mfma_f32_16x16x32_f16(a, b, acc[d], 0, 0, 0);
      }
    }
#pragma unroll
    for (int j4 = 0; j4 < 4; ++j4) {
      uint2 qv = *(const uint2*)&lsq[sch][spart * 16 + j4 * 4];
      uint2 kv = *(const uint2*)&lsk[sch][spart * 16 + j4 * 4];
      qq = fdot2(qv.x, qv.x, qq); qq = fdot2(qv.y, qv.y, qq);
      kk = fdot2(kv.x, kv.x, kk); kk = fdot2(kv.y, kv.y, kk);
    }
  }
  qq += __shfl_xor(qq, 1); qq += __shfl_xor(qq, 2);
  kk += __shfl_xor(kk, 1); kk += __shfl_xor(kk, 2);
  if (spart == 0) {
    pQ[(head * 128 + chunk) * 64 + sch] = qq;
    pK[(head * 128 + chunk) * 64 + sch] = kk;
  }
  float* ps = pS + (size_t)(head * 128 + chunk) * 4096;
#pragma unroll
  for (int d = 0; d < 4; ++d)
#pragma unroll
    for (int r = 0; r < 4; ++r)
      ps[(c0 + lqd * 4 + r) * 64 + d * 16 + ln15] = acc[d][r];
}

// ---------------- K4a: parallel reduce+softmax. Grid (64 c, 4 heads), 256 thr.
__global__ __launch_bounds__(256) void k_softmax(const float* __restrict__ pS,
                                                 const float* __restrict__ pQ,
                                                 const float* __restrict__ pK,
                                                 const float* __restrict__ temp,
                                                 float* __restrict__ A) {
  const int c    = blockIdx.x;    // 0..63
  const int head = blockIdx.y;    // 0..3
  const int tid  = threadIdx.x;
  const int d    = tid & 63, part = tid >> 6;
  __shared__ float red[4][64];
  __shared__ float rq2[128];
  __shared__ float rk[64];
  __shared__ float rqs;

  {
    float s = 0.f;
    for (int ch = part * 32; ch < part * 32 + 32; ++ch)
      s += pK[(head * 128 + ch) * 64 + d];
    red[part][d] = s;
  }
  if (tid < 128) rq2[tid] = pQ[(head * 128 + tid) * 64 + c];
  __syncthreads();
  if (tid < 64) {
    float s = red[0][tid] + red[1][tid] + red[2][tid] + red[3][tid];
    rk[tid] = 1.f / fmaxf(sqrtf(s), 1e-12f);
  }
  if (tid >= 64 && tid < 128) {
    float s = rq2[tid - 64] + rq2[tid];
#pragma unroll
    for (int o = 1; o <= 32; o <<= 1) s += __shfl_xor(s, o);
    if (tid == 64) rqs = 1.f / fmaxf(sqrtf(s), 1e-12f);
  }
  __syncthreads();

  {
    float s = 0.f;
    for (int ch = part * 32; ch < part * 32 + 32; ++ch)
      s += pS[(size_t)(head * 128 + ch) * 4096 + c * 64 + d];
    red[part][d] = s;
  }
  __syncthreads();
  if (tid < 64) {
    const float Sd = red[0][tid] + red[1][tid] + red[2][tid] + red[3][tid];
    float v = Sd * rqs * rk[tid] * temp[head];
    float m = v;
#pragma unroll
    for (int o = 1; o <= 32; o <<= 1) m = fmaxf(m, __shfl_xor(m, o));
    float e = expf(v - m);
    float s = e;
#pragma unroll
    for (int o = 1; o <= 32; o <<= 1) s += __shfl_xor(s, o);
    A[head * 4096 + c * 64 + tid] = e / s;
  }
}

// ---------------- K4b: MtT[oc][h*64+d] = sum_c pw[oc][h*64+c]*A[h][c][d]  (f16)
__global__ __launch_bounds__(64) void k_mt(const float* __restrict__ pw,
                                           const float* __restrict__ A,
                                           ushort* __restrict__ MtT) {
  const int hd = blockIdx.x;   // 0..255
  const int h = hd >> 6, d = hd & 63;
  const int oc = threadIdx.x;  // 0..63
  float s = 0.f;
  for (int c = 0; c < 64; ++c)
    s = fmaf(pw[oc * 256 + h * 64 + c], A[(h * 64 + c) * 64 + d], s);
  MtT[oc * 256 + hd] = f2hs(s);
}

// ---------------- K5: y[oc][n] = sum_hd MtT[oc][hd] * v[hd][n]  via MFMA
__global__ __launch_bounds__(256) void k_pv(const ushort* __restrict__ dwout,
                                            const ushort* __restrict__ MtT,
                                            float* __restrict__ y) {
  const int n0 = blockIdx.x * 64;
  const ushort* vb = dwout + 512 * (size_t)NTOT;
  __shared__ __align__(16) ushort vt[64 * 256];   // 32 KB: [n][hd] quad-rotated
  const int tid = threadIdx.x;
#pragma unroll
  for (int i = 0; i < 2; ++i) {
    const int id = tid + i * 256;    // 0..511
    const int kq = id >> 3;          // hd-quad 0..63
    const int ng = id & 7;           // n-octet
    uint4 r0 = *(const uint4*)(vb + (size_t)(kq * 4 + 0) * NTOT + n0 + ng * 8);
    uint4 r1 = *(const uint4*)(vb + (size_t)(kq * 4 + 1) * NTOT + n0 + ng * 8);
    uint4 r2 = *(const uint4*)(vb + (size_t)(kq * 4 + 2) * NTOT + n0 + ng * 8);
    uint4 r3 = *(const uint4*)(vb + (size_t)(kq * 4 + 3) * NTOT + n0 + ng * 8);
    const ushort* h0 = (const ushort*)&r0;
    const ushort* h1 = (const ushort*)&r1;
    const ushort* h2 = (const ushort*)&r2;
    const ushort* h3 = (const ushort*)&r3;
#pragma unroll
    for (int j = 0; j < 8; ++j) {
      const int n = ng * 8 + j;
      unsigned lo = (unsigned)h0[j] | ((unsigned)h1[j] << 16);
      unsigned hi = (unsigned)h2[j] | ((unsigned)h3[j] << 16);
      const int slot = (kq + n + (n >> 3)) & 63;
      *(uint2*)(vt + n * 256 + slot * 4) = (uint2){lo, hi};
    }
  }
  __syncthreads();

  const int lane = tid & 63;
  const int wv   = tid >> 6;
  const int ln15 = lane & 15, lq = lane >> 4;
  const int nloc = wv * 16 + ln15;
  const int nrot = nloc + (nloc >> 3);

  f32x4 acc[4];
#pragma unroll
  for (int i = 0; i < 4; ++i) acc[i] = (f32x4){0.f, 0.f, 0.f, 0.f};

#pragma unroll
  for (int kb = 0; kb < 8; ++kb) {
    const int kq0 = kb * 8 + lq;
    const int s0 = ((kq0 + nrot) & 63) * 4;
    const int s1 = ((kq0 + 4 + nrot) & 63) * 4;
    f16x4 b0 = *(const f16x4*)(vt + nloc * 256 + s0);
    f16x4 b1 = *(const f16x4*)(vt + nloc * 256 + s1);
    f16x8 b = cmb(b0, b1);
#pragma unroll
    for (int mt = 0; mt < 4; ++mt) {
      const ushort* ap = MtT + (mt * 16 + ln15) * 256 + kb * 32 + lq * 4;
      f16x4 a0 = *(const f16x4*)(ap);
      f16x4 a1 = *(const f16x4*)(ap + 16);
      f16x8 a = cmb(a0, a1);
      acc[mt] = __builtin_amdgcn_mfma_f32_16x16x32_f16(a, b, acc[mt], 0, 0, 0);
    }
  }
  const int n = n0 + nloc;
#pragma unroll
  for (int mt = 0; mt < 4; ++mt) {
    const int oc = mt * 16 + lq * 4;
#pragma unroll
    for (int r = 0; r < 4; ++r)
      y[(size_t)(oc + r) * NTOT + n] = acc[mt][r];
  }
}

extern "C" void kernel_launch(void* const* d_in, const int* in_sizes, int n_in,
                              void* d_out, int out_size, void* d_ws, size_t ws_size,
                              hipStream_t stream) {
  const float* x      = (const float*)d_in[0];
  const float* qkv_w  = (const float*)d_in[1];
  const float* dw_w   = (const float*)d_in[2];
  const float* proj_w = (const float*)d_in[3];
  const float* temp   = (const float*)d_in[4];
  float* out = (float*)d_out;

  char* w8 = (char*)d_ws;
  ushort* qkvT = (ushort*)(w8);                        // [48][65536][16] f16 = 100,663,296 B
  ushort* dwout = (ushort*)(w8 + 100663296ull);        // [768][n] f16 = 100,663,296 B
  float* pS    = (float*)(w8 + 201326592ull);          // 4*128*4096 f32 = 8,388,608 B
  float* pQ    = (float*)(w8 + 209715200ull);          // 32768 f32
  float* pK    = (float*)(w8 + 209846272ull);          // 32768 f32
  float* A     = (float*)(w8 + 209977344ull);          // 16384 f32
  ushort* MtT  = (ushort*)(w8 + 210042880ull);         // 64*256 f16 = 32768 B
  // total ~210 MB

  k_qkv<<<dim3(1024, 12), 256, 0, stream>>>(x, qkv_w, qkvT);
  k_dwconv<<<dim3(48, 128), 256, 0, stream>>>(qkvT, dw_w, dwout);
  k_attn_part<<<dim3(128, 4), 256, 0, stream>>>(dwout, pS, pQ, pK);
  k_softmax<<<dim3(64, 4), 256, 0, stream>>>(pS, pQ, pK, temp, A);
  k_mt<<<256, 64, 0, stream>>>(proj_w, A, MtT);
  k_pv<<<1024, 256, 0, stream>>>(dwout, MtT, out);
}

// Round 21
// 147.564 us; speedup vs baseline: 1.0272x; 1.0133x over previous
//
#include <hip/hip_runtime.h>
#include <hip/hip_bf16.h>
#include <hip/hip_fp16.h>

#define NTOT 65536   // T*H*W

typedef __hip_bfloat16 bf16;
typedef _Float16 f16;
typedef f16 f16x4 __attribute__((ext_vector_type(4)));
typedef f16 f16x8 __attribute__((ext_vector_type(8)));
typedef float f32x4 __attribute__((ext_vector_type(4)));
typedef _Float16 h2f16 __attribute__((ext_vector_type(2)));

__device__ __forceinline__ ushort f2hs(float f) {
  __half h = __float2half(f);
  return __half_as_ushort(h);
}
__device__ __forceinline__ f16 us2h(ushort u) {
  return __builtin_bit_cast(f16, u);
}
__device__ __forceinline__ float fdot2(unsigned a, unsigned b, float c) {
  return __builtin_amdgcn_fdot2(__builtin_bit_cast(h2f16, a),
                                __builtin_bit_cast(h2f16, b), c, false);
}
__device__ __forceinline__ f16x8 cmb(f16x4 a, f16x4 b) {
  f16x8 r;
#pragma unroll
  for (int j = 0; j < 4; ++j) { r[j] = a[j]; r[j + 4] = b[j]; }
  return r;
}

// ---------------- K1: 1x1x1 conv as MFMA GEMM; qkvT[cluster][n][16ch] f16
__global__ __launch_bounds__(256) void k_qkv(const float* __restrict__ x,
                                             const float* __restrict__ w,
                                             ushort* __restrict__ qkvT) {
  const int n0  = blockIdx.x * 64;
  const int oct = blockIdx.y;           // 0..11
  __shared__ __align__(16) ushort wt[64 * 72];     // 9216 B
  const int tid = threadIdx.x;
  const float4* w4 = (const float4*)w;
#pragma unroll
  for (int i = 0; i < 4; ++i) {
    const int idx = tid + i * 256;      // 0..1023
    const int oc = idx >> 4, kq = idx & 15;
    float4 wv = w4[(oct * 64 + oc) * 16 + kq];
    ushort4 o;
    o.x = f2hs(wv.x); o.y = f2hs(wv.y); o.z = f2hs(wv.z); o.w = f2hs(wv.w);
    *(ushort4*)(wt + oc * 72 + kq * 4) = o;
  }
  __syncthreads();

  const int lane = tid & 63;
  const int wq   = tid >> 6;
  const int ln15 = lane & 15;
  const int lq   = lane >> 4;
  const int n    = n0 + wq * 16 + ln15;

  f32x4 acc[4];
#pragma unroll
  for (int i = 0; i < 4; ++i) acc[i] = (f32x4){0.f, 0.f, 0.f, 0.f};

#pragma unroll
  for (int kk = 0; kk < 4; ++kk) {
    const int kb = kk * 4 + lq;         // k-quad index; k = kb*4 + j
    f16x4 b;
#pragma unroll
    for (int j = 0; j < 4; ++j)
      b[j] = (f16)x[(size_t)(kb * 4 + j) * NTOT + n];
#pragma unroll
    for (int mt = 0; mt < 4; ++mt) {
      f16x4 a = *(const f16x4*)(wt + (mt * 16 + ln15) * 72 + kk * 16 + lq * 4);
      acc[mt] = __builtin_amdgcn_mfma_f32_16x16x16f16(a, b, acc[mt], 0, 0, 0);
    }
  }
#pragma unroll
  for (int mt = 0; mt < 4; ++mt) {
    const int cl = oct * 4 + mt;
    ushort4 o;
    o.x = f2hs(acc[mt][0]);
    o.y = f2hs(acc[mt][1]);
    o.z = f2hs(acc[mt][2]);
    o.w = f2hs(acc[mt][3]);
    *(ushort4*)(qkvT + ((size_t)cl * NTOT + n) * 16 + lq * 4) = o;
  }
}

// ---------------- K2: grouped 3x3x3 conv, block-diag implicit GEMM on MFMA K=16.
__global__ __launch_bounds__(256, 4) void k_dwconv(const ushort* __restrict__ qkvT,
                                                   const float* __restrict__ dww,
                                                   ushort* __restrict__ out) {
  const int cl = blockIdx.x;        // 0..47
  const int s  = blockIdx.y;        // 0..127
  const int wsel = s & 3, hsel = (s >> 2) & 7, tsel = s >> 5;
  const int t0 = tsel * 4, h0 = hsel * 8, w0 = wsel * 16;
  __shared__ __align__(16) ushort xh[6 * 10 * 18 * 16];  // 34560 B
  __shared__ __align__(16) ushort at[27 * 64];           //  3456 B [tap][p16][ic4]
  const int tid = threadIdx.x;

  const ushort* cb = qkvT + (size_t)cl * (NTOT * 16);
  uint4 ha[5], hb[5];
#pragma unroll
  for (int i = 0; i < 5; ++i) {
    const int ci = tid + i * 256;
    uint4 d0 = {0, 0, 0, 0}, d1 = {0, 0, 0, 0};
    if (ci < 1080) {
      const int W = ci % 18;
      const int r = ci / 18;
      const int H = r % 10;
      const int T = r / 10;
      const int Tg = t0 - 1 + T, Hg = h0 - 1 + H, Wg = w0 - 1 + W;
      if ((unsigned)Tg < 16u && (unsigned)Hg < 64u && (unsigned)Wg < 64u) {
        const uint4* src = (const uint4*)(cb + (size_t)(Tg * 4096 + Hg * 64 + Wg) * 16);
        d0 = src[0];
        d1 = src[1];
      }
    }
    ha[i] = d0;
    hb[i] = d1;
  }
  for (int idx = tid; idx < 27 * 64; idx += 256) {
    int tap = idx >> 6;
    int p   = (idx >> 2) & 15;
    int ic  = idx & 3;
    at[idx] = f2hs(dww[(cl * 4 + (p >> 2)) * 432 + ((p & 3) * 4 + ic) * 27 + tap]);
  }
#pragma unroll
  for (int i = 0; i < 5; ++i) {
    const int ci = tid + i * 256;
    if (ci < 1080) {
      const int W = ci % 18;
      const int rot = (W >> 2) & 3;
      uint2* dst = (uint2*)(xh + ci * 16);
      uint2 u0 = {ha[i].x, ha[i].y}, u1 = {ha[i].z, ha[i].w};
      uint2 u2 = {hb[i].x, hb[i].y}, u3 = {hb[i].z, hb[i].w};
      dst[(0 + rot) & 3] = u0;
      dst[(1 + rot) & 3] = u1;
      dst[(2 + rot) & 3] = u2;
      dst[(3 + rot) & 3] = u3;
    }
  }
  __syncthreads();

  const int lane = tid & 63;
  const int wv   = tid >> 6;        // h-pair index: wave covers h = wv*2, wv*2+1
  const int hp   = wv * 2;
  const int ln15 = lane & 15;
  const int lq   = lane >> 4;
  const bool diag = (lq == (ln15 >> 2));
  const ushort* bp[3];
#pragma unroll
  for (int dwp = 0; dwp < 3; ++dwp) {
    const int Wl = ln15 + dwp;
    const int slot = (lq + (Wl >> 2)) & 3;
    bp[dwp] = xh + Wl * 16 + slot * 4;
  }
  const f16x4 z4 = {};

  f32x4 acc[4][2];   // [t][h2]
#pragma unroll
  for (int a = 0; a < 4; ++a)
#pragma unroll
    for (int b = 0; b < 2; ++b) acc[a][b] = (f32x4){0.f, 0.f, 0.f, 0.f};

#pragma unroll
  for (int dh = 0; dh < 3; ++dh) {
#pragma unroll
    for (int dwp = 0; dwp < 3; ++dwp) {
      f16x4 B[6][2];
#pragma unroll
      for (int tt = 0; tt < 6; ++tt)
#pragma unroll
        for (int h2 = 0; h2 < 2; ++h2)
          B[tt][h2] = *(const f16x4*)(bp[dwp] + (tt * 10 + hp + h2 + dh) * 288);
#pragma unroll
      for (int dt = 0; dt < 3; ++dt) {
        const int tap = (dt * 3 + dh) * 3 + dwp;
        f16x4 a = *(const f16x4*)(at + tap * 64 + ln15 * 4);
        if (!diag) a = z4;
#pragma unroll
        for (int t = 0; t < 4; ++t)
#pragma unroll
          for (int h2 = 0; h2 < 2; ++h2)
            acc[t][h2] = __builtin_amdgcn_mfma_f32_16x16x16f16(a, B[t + dt][h2],
                                                               acc[t][h2], 0, 0, 0);
      }
    }
  }
  const int chbase = cl * 16 + lq * 4;
#pragma unroll
  for (int t = 0; t < 4; ++t)
#pragma unroll
    for (int h2 = 0; h2 < 2; ++h2) {
      const int n = (t0 + t) * 4096 + (h0 + hp + h2) * 64 + w0 + ln15;
#pragma unroll
      for (int r = 0; r < 4; ++r)
        out[(size_t)(chbase + r) * NTOT + n] = f2hs(acc[t][h2][r]);
    }
}

// ---------------- K3: gram via MFMA. S[c][d] = sum_n q[c][n]k[d][n]; + sum q^2,k^2
__global__ __launch_bounds__(256) void k_attn_part(const ushort* __restrict__ dwout,
                                                   float* __restrict__ pS,
                                                   float* __restrict__ pQ,
                                                   float* __restrict__ pK) {
  const int head = blockIdx.y;
  const int chunk = blockIdx.x;   // 0..127, each 512 n
  const int tid = threadIdx.x;
  const ushort* qb = dwout + (size_t)(head * 64) * NTOT;
  const ushort* kb = dwout + (size_t)(256 + head * 64) * NTOT;
  __shared__ __align__(16) ushort lsq[64][76];   // 9728 B, row 152B
  __shared__ __align__(16) ushort lsk[64][76];
  const int lane = tid & 63, wv = tid >> 6;
  const int ln15 = lane & 15, lqd = lane >> 4;
  const int c0 = wv * 16;
  const int sch = tid >> 2, spart = tid & 3;
  f32x4 acc[4];
#pragma unroll
  for (int i = 0; i < 4; ++i) acc[i] = (f32x4){0.f, 0.f, 0.f, 0.f};
  float qq = 0.f, kk = 0.f;

  for (int ph = 0; ph < 8; ++ph) {
    const int nb = chunk * 512 + ph * 64;
    __syncthreads();
#pragma unroll
    for (int i = 0; i < 2; ++i) {
      const int id = tid + i * 256;   // 0..511
      const int ch = id >> 3, n8 = id & 7;
      uint4 qv = *(const uint4*)(qb + (size_t)ch * NTOT + nb + n8 * 8);
      uint4 kv = *(const uint4*)(kb + (size_t)ch * NTOT + nb + n8 * 8);
      *(uint2*)&lsq[ch][n8 * 8]     = (uint2){qv.x, qv.y};
      *(uint2*)&lsq[ch][n8 * 8 + 4] = (uint2){qv.z, qv.w};
      *(uint2*)&lsk[ch][n8 * 8]     = (uint2){kv.x, kv.y};
      *(uint2*)&lsk[ch][n8 * 8 + 4] = (uint2){kv.z, kv.w};
    }
    __syncthreads();
#pragma unroll
    for (int ks = 0; ks < 2; ++ks) {
      f16x4 a0 = *(const f16x4*)&lsq[c0 + ln15][ks * 32 + lqd * 4];
      f16x4 a1 = *(const f16x4*)&lsq[c0 + ln15][ks * 32 + lqd * 4 + 16];
      f16x8 a = cmb(a0, a1);
#pragma unroll
      for (int d = 0; d < 4; ++d) {
        f16x4 b0 = *(const f16x4*)&lsk[d * 16 + ln15][ks * 32 + lqd * 4];
        f16x4 b1 = *(const f16x4*)&lsk[d * 16 + ln15][ks * 32 + lqd * 4 + 16];
        f16x8 b = cmb(b0, b1);
        acc[d] = __builtin_amdgcn_mfma_f32_16x16x32_f16(a, b, acc[d], 0, 0, 0);
      }
    }
#pragma unroll
    for (int j4 = 0; j4 < 4; ++j4) {
      uint2 qv = *(const uint2*)&lsq[sch][spart * 16 + j4 * 4];
      uint2 kv = *(const uint2*)&lsk[sch][spart * 16 + j4 * 4];
      qq = fdot2(qv.x, qv.x, qq); qq = fdot2(qv.y, qv.y, qq);
      kk = fdot2(kv.x, kv.x, kk); kk = fdot2(kv.y, kv.y, kk);
    }
  }
  qq += __shfl_xor(qq, 1); qq += __shfl_xor(qq, 2);
  kk += __shfl_xor(kk, 1); kk += __shfl_xor(kk, 2);
  if (spart == 0) {
    pQ[(head * 128 + chunk) * 64 + sch] = qq;
    pK[(head * 128 + chunk) * 64 + sch] = kk;
  }
  float* ps = pS + (size_t)(head * 128 + chunk) * 4096;
#pragma unroll
  for (int d = 0; d < 4; ++d)
#pragma unroll
    for (int r = 0; r < 4; ++r)
      ps[(c0 + lqd * 4 + r) * 64 + d * 16 + ln15] = acc[d][r];
}

// ---------------- K4a: parallel reduce+softmax. Grid (64 c, 4 heads), 256 thr.
__global__ __launch_bounds__(256) void k_softmax(const float* __restrict__ pS,
                                                 const float* __restrict__ pQ,
                                                 const float* __restrict__ pK,
                                                 const float* __restrict__ temp,
                                                 float* __restrict__ A) {
  const int c    = blockIdx.x;    // 0..63
  const int head = blockIdx.y;    // 0..3
  const int tid  = threadIdx.x;
  const int d    = tid & 63, part = tid >> 6;
  __shared__ float red[4][64];
  __shared__ float rq2[128];
  __shared__ float rk[64];
  __shared__ float rqs;

  {
    float s = 0.f;
    for (int ch = part * 32; ch < part * 32 + 32; ++ch)
      s += pK[(head * 128 + ch) * 64 + d];
    red[part][d] = s;
  }
  if (tid < 128) rq2[tid] = pQ[(head * 128 + tid) * 64 + c];
  __syncthreads();
  if (tid < 64) {
    float s = red[0][tid] + red[1][tid] + red[2][tid] + red[3][tid];
    rk[tid] = 1.f / fmaxf(sqrtf(s), 1e-12f);
  }
  if (tid >= 64 && tid < 128) {
    float s = rq2[tid - 64] + rq2[tid];
#pragma unroll
    for (int o = 1; o <= 32; o <<= 1) s += __shfl_xor(s, o);
    if (tid == 64) rqs = 1.f / fmaxf(sqrtf(s), 1e-12f);
  }
  __syncthreads();

  {
    float s = 0.f;
    for (int ch = part * 32; ch < part * 32 + 32; ++ch)
      s += pS[(size_t)(head * 128 + ch) * 4096 + c * 64 + d];
    red[part][d] = s;
  }
  __syncthreads();
  if (tid < 64) {
    const float Sd = red[0][tid] + red[1][tid] + red[2][tid] + red[3][tid];
    float v = Sd * rqs * rk[tid] * temp[head];
    float m = v;
#pragma unroll
    for (int o = 1; o <= 32; o <<= 1) m = fmaxf(m, __shfl_xor(m, o));
    float e = expf(v - m);
    float s = e;
#pragma unroll
    for (int o = 1; o <= 32; o <<= 1) s += __shfl_xor(s, o);
    A[head * 4096 + c * 64 + tid] = e / s;
  }
}

// ---------------- K4b: MtT[oc][h*64+d] = sum_c pw[oc][h*64+c]*A[h][c][d]  (f16)
__global__ __launch_bounds__(64) void k_mt(const float* __restrict__ pw,
                                           const float* __restrict__ A,
                                           ushort* __restrict__ MtT) {
  const int hd = blockIdx.x;   // 0..255
  const int h = hd >> 6, d = hd & 63;
  const int oc = threadIdx.x;  // 0..63
  float s = 0.f;
  for (int c = 0; c < 64; ++c)
    s = fmaf(pw[oc * 256 + h * 64 + c], A[(h * 64 + c) * 64 + d], s);
  MtT[oc * 256 + hd] = f2hs(s);
}

// ---------------- K5: y[oc][n] = sum_hd MtT[oc][hd] * v[hd][n]  via MFMA
// B-fragments read DIRECTLY from global v (lane-consecutive n = coalesced;
// each element read once grid-wide, L3-resident). No LDS, no barrier.
__global__ __launch_bounds__(256) void k_pv(const ushort* __restrict__ dwout,
                                            const ushort* __restrict__ MtT,
                                            float* __restrict__ y) {
  const int n0 = blockIdx.x * 64;
  const ushort* vb = dwout + 512 * (size_t)NTOT;
  const int tid = threadIdx.x;
  const int lane = tid & 63;
  const int wv   = tid >> 6;
  const int ln15 = lane & 15, lq = lane >> 4;
  const int n = n0 + wv * 16 + ln15;

  f32x4 acc[4];
#pragma unroll
  for (int i = 0; i < 4; ++i) acc[i] = (f32x4){0.f, 0.f, 0.f, 0.f};

#pragma unroll
  for (int kb = 0; kb < 8; ++kb) {
    const int hd0 = kb * 32 + lq * 4;
    f16x4 b0, b1;
#pragma unroll
    for (int j = 0; j < 4; ++j) {
      b0[j] = us2h(vb[(size_t)(hd0 + j) * NTOT + n]);
      b1[j] = us2h(vb[(size_t)(hd0 + 16 + j) * NTOT + n]);
    }
    f16x8 b = cmb(b0, b1);
#pragma unroll
    for (int mt = 0; mt < 4; ++mt) {
      const ushort* ap = MtT + (mt * 16 + ln15) * 256 + kb * 32 + lq * 4;
      f16x4 a0 = *(const f16x4*)(ap);
      f16x4 a1 = *(const f16x4*)(ap + 16);
      f16x8 a = cmb(a0, a1);
      acc[mt] = __builtin_amdgcn_mfma_f32_16x16x32_f16(a, b, acc[mt], 0, 0, 0);
    }
  }
#pragma unroll
  for (int mt = 0; mt < 4; ++mt) {
    const int oc = mt * 16 + lq * 4;
#pragma unroll
    for (int r = 0; r < 4; ++r)
      y[(size_t)(oc + r) * NTOT + n] = acc[mt][r];
  }
}

extern "C" void kernel_launch(void* const* d_in, const int* in_sizes, int n_in,
                              void* d_out, int out_size, void* d_ws, size_t ws_size,
                              hipStream_t stream) {
  const float* x      = (const float*)d_in[0];
  const float* qkv_w  = (const float*)d_in[1];
  const float* dw_w   = (const float*)d_in[2];
  const float* proj_w = (const float*)d_in[3];
  const float* temp   = (const float*)d_in[4];
  float* out = (float*)d_out;

  char* w8 = (char*)d_ws;
  ushort* qkvT = (ushort*)(w8);                        // [48][65536][16] f16 = 100,663,296 B
  ushort* dwout = (ushort*)(w8 + 100663296ull);        // [768][n] f16 = 100,663,296 B
  float* pS    = (float*)(w8 + 201326592ull);          // 4*128*4096 f32 = 8,388,608 B
  float* pQ    = (float*)(w8 + 209715200ull);          // 32768 f32
  float* pK    = (float*)(w8 + 209846272ull);          // 32768 f32
  float* A     = (float*)(w8 + 209977344ull);          // 16384 f32
  ushort* MtT  = (ushort*)(w8 + 210042880ull);         // 64*256 f16 = 32768 B
  // total ~210 MB

  k_qkv<<<dim3(1024, 12), 256, 0, stream>>>(x, qkv_w, qkvT);
  k_dwconv<<<dim3(48, 128), 256, 0, stream>>>(qkvT, dw_w, dwout);
  k_attn_part<<<dim3(128, 4), 256, 0, stream>>>(dwout, pS, pQ, pK);
  k_softmax<<<dim3(64, 4), 256, 0, stream>>>(pS, pQ, pK, temp, A);
  k_mt<<<256, 64, 0, stream>>>(proj_w, A, MtT);
  k_pv<<<1024, 256, 0, stream>>>(dwout, MtT, out);
}